// Round 1
// baseline (666.169 us; speedup 1.0000x reference)
//
#include <hip/hip_runtime.h>
#include <math.h>

// Problem constants
#define B_    8
#define L_    512
#define K_    16
#define E_    32
#define NH_   64
#define WOFF_ 1

// Workspace layout (floats):
//   qmat  [B][L][32]   @ 0        (131072)
//   kmatT [B][32][L]   @ 131072   (131072)  (transposed: d-major for coalesced score loads)
//   att   [B][L][64]   @ 262144   (262144)
//   gi    [B][L][192]  @ 524288   (786432)
// total 1,310,720 floats = 5.25 MB

// ---------------------------------------------------------------------------
// Kernel 1: key_emb -> q, k projections. One thread per (b,l).
// ---------------------------------------------------------------------------
__global__ __launch_bounds__(256) void k_embed(
    const float* __restrict__ ts, const float* __restrict__ Wl,
    const float* __restrict__ bl, const float* __restrict__ Wp,
    const float* __restrict__ bp, const float* __restrict__ Wq,
    const float* __restrict__ bq, const float* __restrict__ Wk,
    const float* __restrict__ bk,
    float* __restrict__ qmat, float* __restrict__ kmatT)
{
    __shared__ float WqL[1024], WkL[1024];
    __shared__ float bqL[32], bkL[32], WpL[31], bpL[31];
    __shared__ float wl0, bl0;
    const int tid = threadIdx.x;

    // stage weights (Wq/Wk are 256 float4 each)
    {
        float4 v = ((const float4*)Wq)[tid];
        ((float4*)WqL)[tid] = v;
        float4 u = ((const float4*)Wk)[tid];
        ((float4*)WkL)[tid] = u;
    }
    if (tid < 32) { bqL[tid] = bq[tid]; bkL[tid] = bk[tid]; }
    if (tid < 31) { WpL[tid] = Wp[tid]; bpL[tid] = bp[tid]; }
    if (tid == 0) { wl0 = Wl[0]; bl0 = bl[0]; }
    __syncthreads();

    const int p = blockIdx.x * 256 + tid;      // 0..4095
    const float t = ts[p];
    float e[32];
    e[0] = t * wl0 + bl0;
    #pragma unroll
    for (int j = 1; j < 32; ++j) e[j] = sinf(t * WpL[j - 1] + bpL[j - 1]);

    const int b = p >> 9, l = p & 511;
    float4* qm4 = (float4*)(qmat + (size_t)p * 32);
    float*  kT  = kmatT + (size_t)b * 32 * 512 + l;

    for (int dq = 0; dq < 8; ++dq) {
        float q0 = bqL[4*dq+0], q1 = bqL[4*dq+1], q2 = bqL[4*dq+2], q3 = bqL[4*dq+3];
        float k0 = bkL[4*dq+0], k1 = bkL[4*dq+1], k2 = bkL[4*dq+2], k3 = bkL[4*dq+3];
        const float* wq = &WqL[(4*dq) * 32];
        const float* wk = &WkL[(4*dq) * 32];
        #pragma unroll
        for (int j = 0; j < 32; ++j) {
            const float ej = e[j];
            q0 = fmaf(wq[j],      ej, q0);
            q1 = fmaf(wq[32 + j], ej, q1);
            q2 = fmaf(wq[64 + j], ej, q2);
            q3 = fmaf(wq[96 + j], ej, q3);
            k0 = fmaf(wk[j],      ej, k0);
            k1 = fmaf(wk[32 + j], ej, k1);
            k2 = fmaf(wk[64 + j], ej, k2);
            k3 = fmaf(wk[96 + j], ej, k3);
        }
        qm4[dq] = make_float4(q0, q1, q2, q3);
        kT[(4*dq + 0) * 512] = k0;   // coalesced: consecutive lanes -> consecutive l
        kT[(4*dq + 1) * 512] = k1;
        kT[(4*dq + 2) * 512] = k2;
        kT[(4*dq + 3) * 512] = k3;
    }
}

// ---------------------------------------------------------------------------
// Kernel 2: per-(b,q) attention -> att_out.  grid (32 qb, 8 b), 256 thr.
// Wave w handles q = qb*16 + w*4 + iq. Scores -> LDS row, then per-category
// online softmax with lane = (category, segment-of-128) and shfl merge.
// ---------------------------------------------------------------------------
__global__ __launch_bounds__(256) void k_attn(
    const float* __restrict__ qmat, const float* __restrict__ kmatT,
    const float* __restrict__ val,  const int*   __restrict__ mark,
    const float* __restrict__ npm,  const float* __restrict__ Wo,
    const float* __restrict__ bo,   float* __restrict__ att)
{
    __shared__ float srow[4 * 512];   // per-wave score row
    __shared__ int   cc[512];         // category (-1 if padded)
    __shared__ float vv[512];         // values
    const int tid = threadIdx.x;
    const int qb  = blockIdx.x;       // 0..31
    const int b   = blockIdx.y;       // 0..7

    for (int k = tid; k < 512; k += 256) {
        const int   m  = mark[b * 512 + k];
        const float np = npm[b * 512 + k];
        cc[k] = (np > 0.0f) ? (m - 1) : -1;
        vv[k] = val[b * 512 + k];
    }
    __syncthreads();

    const int w = tid >> 6, lane = tid & 63;
    const float* kTb = kmatT + (size_t)b * 32 * 512;

    for (int iq = 0; iq < 4; ++iq) {
        const int q = qb * 16 + w * 4 + iq;

        // qvec (broadcast loads)
        float qr[32];
        const float4* qm4 = (const float4*)(qmat + (size_t)(b * 512 + q) * 32);
        #pragma unroll
        for (int j4 = 0; j4 < 8; ++j4) {
            float4 v = qm4[j4];
            qr[4*j4+0] = v.x; qr[4*j4+1] = v.y; qr[4*j4+2] = v.z; qr[4*j4+3] = v.w;
        }

        // scores: lane computes k = m*64 + lane, coalesced reads of kmatT
        float acc[8];
        #pragma unroll
        for (int m = 0; m < 8; ++m) acc[m] = 0.0f;
        #pragma unroll 4
        for (int j = 0; j < 32; ++j) {
            const float* row = kTb + j * 512 + lane;
            const float  qj  = qr[j];
            #pragma unroll
            for (int m = 0; m < 8; ++m) acc[m] = fmaf(qj, row[m * 64], acc[m]);
        }
        #pragma unroll
        for (int m = 0; m < 8; ++m)
            srow[w * 512 + m * 64 + lane] = acc[m] * 0.17677669529663687f; // 1/sqrt(32)
        __syncthreads();

        // phase 2: per-category online softmax.  lane = c + 16*s
        const int c = lane & 15, s = lane >> 4;
        float mx = -1e30f, Z = 0.0f, X = 0.0f;
        const int base = s * 128;
        for (int t = 0; t < 128; ++t) {
            const int k = base + ((t + s) & 127);   // rotate to avoid bank clash
            if (cc[k] == c) {
                const float l  = (k <= q + WOFF_) ? srow[w * 512 + k] : 0.0f;
                const float mn = fmaxf(mx, l);
                const float e1 = __expf(l - mn);
                const float sc = __expf(mx - mn);
                Z = Z * sc + e1;
                X = X * sc + e1 * vv[k];
                mx = mn;
            }
        }
        // merge the 4 segments (lanes c+0,16,32,48)
        #pragma unroll
        for (int off = 16; off <= 32; off <<= 1) {
            const float mo = __shfl_xor(mx, off);
            const float Zo = __shfl_xor(Z, off);
            const float Xo = __shfl_xor(X, off);
            const float mn = fmaxf(mx, mo);
            const float a0 = __expf(mx - mn);
            const float a1 = __expf(mo - mn);
            Z = Z * a0 + Zo * a1;
            X = X * a0 + Xo * a1;
            mx = mn;
        }
        const float x = (Z > 0.0f) ? X / Z : 0.0f;

        float xs[16];
        #pragma unroll
        for (int c2 = 0; c2 < 16; ++c2) xs[c2] = __shfl(x, c2);

        // att_out row: lane = output channel n
        const float4* wo4 = (const float4*)(Wo + lane * 16);
        float a = bo[lane];
        #pragma unroll
        for (int c4 = 0; c4 < 4; ++c4) {
            float4 v = wo4[c4];
            a += xs[4*c4+0] * v.x + xs[4*c4+1] * v.y + xs[4*c4+2] * v.z + xs[4*c4+3] * v.w;
        }
        att[(size_t)(b * 512 + q) * 64 + lane] = a;
        __syncthreads();
    }
}

// ---------------------------------------------------------------------------
// Kernel 3: gi = att @ W_ih^T + b_ih.  256 blocks x 16 rows each.
// W_ih staged in LDS with row pad 65 (bank-conflict-free dot reads).
// ---------------------------------------------------------------------------
__global__ __launch_bounds__(256) void k_gi(
    const float* __restrict__ att, const float* __restrict__ Wih,
    const float* __restrict__ bih, float* __restrict__ gi)
{
    __shared__ float WL[192 * 65];
    __shared__ float attL[16 * 64];
    __shared__ float bL[192];
    const int tid = threadIdx.x;

    for (int idx = tid; idx < 3072; idx += 256) {        // 192*64/4 float4s
        float4 v = ((const float4*)Wih)[idx];
        const int g = idx >> 4, jq = idx & 15;
        float* dst = &WL[g * 65 + jq * 4];
        dst[0] = v.x; dst[1] = v.y; dst[2] = v.z; dst[3] = v.w;
    }
    if (tid < 192) bL[tid] = bih[tid];
    {
        float4 v = ((const float4*)att)[blockIdx.x * 256 + tid];
        ((float4*)attL)[tid] = v;
    }
    __syncthreads();

    const size_t out0 = (size_t)blockIdx.x * 16 * 192;
    for (int pp = 0; pp < 12; ++pp) {
        const int p = tid + 256 * pp;                    // < 3072
        const int r = p / 192, g = p - r * 192;
        float a0 = bL[g], a1 = 0.f, a2 = 0.f, a3 = 0.f;
        const float* wrow = &WL[g * 65];
        const float* arow = &attL[r * 64];
        #pragma unroll
        for (int j = 0; j < 64; j += 4) {
            a0 = fmaf(arow[j + 0], wrow[j + 0], a0);
            a1 = fmaf(arow[j + 1], wrow[j + 1], a1);
            a2 = fmaf(arow[j + 2], wrow[j + 2], a2);
            a3 = fmaf(arow[j + 3], wrow[j + 3], a3);
        }
        gi[out0 + p] = (a0 + a1) + (a2 + a3);            // (r,g) -> p contiguous
    }
}

// ---------------------------------------------------------------------------
// Kernel 4: sequential GRU. One block per batch, 192 threads (one per gate).
// W_hh rows in registers; h broadcast via LDS; 2 barriers per step.
// ---------------------------------------------------------------------------
__global__ __launch_bounds__(192) void k_gru(
    const float* __restrict__ gi, const float* __restrict__ Whh,
    const float* __restrict__ bhh, float* __restrict__ out)
{
    __shared__ __align__(16) float hs[64];
    __shared__ float ghL[192];
    const int tid = threadIdx.x;
    const int b   = blockIdx.x;

    float wh[64];
    const float4* w4 = (const float4*)(Whh + tid * 64);
    #pragma unroll
    for (int j4 = 0; j4 < 16; ++j4) {
        float4 v = w4[j4];
        wh[4*j4+0] = v.x; wh[4*j4+1] = v.y; wh[4*j4+2] = v.z; wh[4*j4+3] = v.w;
    }
    const float bh = bhh[tid];
    if (tid < 64) hs[tid] = 0.0f;
    __syncthreads();

    const float* gib  = gi  + (size_t)b * 512 * 192;
    float*       outb = out + (size_t)b * 512 * 64;

    for (int t = 0; t < 512; ++t) {
        float a0 = bh, a1 = 0.f, a2 = 0.f, a3 = 0.f;
        const float4* h4 = (const float4*)hs;
        #pragma unroll
        for (int j4 = 0; j4 < 16; ++j4) {
            float4 v = h4[j4];
            a0 = fmaf(wh[4*j4+0], v.x, a0);
            a1 = fmaf(wh[4*j4+1], v.y, a1);
            a2 = fmaf(wh[4*j4+2], v.z, a2);
            a3 = fmaf(wh[4*j4+3], v.w, a3);
        }
        ghL[tid] = (a0 + a1) + (a2 + a3);
        __syncthreads();
        if (tid < 64) {
            const float* git = gib + t * 192;
            const float gr = git[tid], gz = git[tid + 64], gn = git[tid + 128];
            const float hr = ghL[tid], hz = ghL[tid + 64], hn = ghL[tid + 128];
            const float r = 1.0f / (1.0f + __expf(-(gr + hr)));
            const float z = 1.0f / (1.0f + __expf(-(gz + hz)));
            const float n = tanhf(gn + r * hn);
            const float hnew = (1.0f - z) * n + z * hs[tid];
            outb[t * 64 + tid] = hnew;
            hs[tid] = hnew;
        }
        __syncthreads();
    }
}

// ---------------------------------------------------------------------------
extern "C" void kernel_launch(void* const* d_in, const int* in_sizes, int n_in,
                              void* d_out, int out_size, void* d_ws, size_t ws_size,
                              hipStream_t stream)
{
    const float* ts   = (const float*)d_in[0];
    const float* val  = (const float*)d_in[1];
    const int*   mark = (const int*)  d_in[2];
    const float* npm  = (const float*)d_in[3];
    const float* Wl   = (const float*)d_in[4];
    const float* bl   = (const float*)d_in[5];
    const float* Wp   = (const float*)d_in[6];
    const float* bp   = (const float*)d_in[7];
    const float* Wq   = (const float*)d_in[8];
    const float* bq   = (const float*)d_in[9];
    const float* Wk   = (const float*)d_in[10];
    const float* bk   = (const float*)d_in[11];
    const float* Wo   = (const float*)d_in[12];
    const float* bo   = (const float*)d_in[13];
    const float* Wih  = (const float*)d_in[14];
    const float* Whh  = (const float*)d_in[15];
    const float* bih  = (const float*)d_in[16];
    const float* bhh  = (const float*)d_in[17];

    float* ws    = (float*)d_ws;
    float* qmat  = ws;                 // 131072
    float* kmatT = ws + 131072;        // 131072
    float* att   = ws + 262144;        // 262144
    float* gi    = ws + 524288;        // 786432
    float* out   = (float*)d_out;

    k_embed<<<16, 256, 0, stream>>>(ts, Wl, bl, Wp, bp, Wq, bq, Wk, bk, qmat, kmatT);
    k_attn<<<dim3(32, 8), 256, 0, stream>>>(qmat, kmatT, val, mark, npm, Wo, bo, att);
    k_gi<<<256, 256, 0, stream>>>(att, Wih, bih, gi);
    k_gru<<<8, 192, 0, stream>>>(gi, Whh, bhh, out);
}

// Round 2
// 656.549 us; speedup vs baseline: 1.0147x; 1.0147x over previous
//
#include <hip/hip_runtime.h>
#include <math.h>

// Problem constants
#define B_    8
#define L_    512
#define K_    16
#define E_    32
#define NH_   64
#define WOFF_ 1

// Workspace layout (floats):
//   qmat  [B][L][32]   @ 0        (131072)
//   kmatT [B][32][L]   @ 131072   (131072)
//   att   [B][L][64]   @ 262144   (262144)
//   gi    [B][L][192]  @ 524288   (786432)

// ---------------------------------------------------------------------------
// Kernel 1: key_emb -> q, k projections. One thread per (b,l).
// ---------------------------------------------------------------------------
__global__ __launch_bounds__(256) void k_embed(
    const float* __restrict__ ts, const float* __restrict__ Wl,
    const float* __restrict__ bl, const float* __restrict__ Wp,
    const float* __restrict__ bp, const float* __restrict__ Wq,
    const float* __restrict__ bq, const float* __restrict__ Wk,
    const float* __restrict__ bk,
    float* __restrict__ qmat, float* __restrict__ kmatT)
{
    __shared__ float WqL[1024], WkL[1024];
    __shared__ float bqL[32], bkL[32], WpL[31], bpL[31];
    __shared__ float wl0, bl0;
    const int tid = threadIdx.x;

    {
        float4 v = ((const float4*)Wq)[tid];
        ((float4*)WqL)[tid] = v;
        float4 u = ((const float4*)Wk)[tid];
        ((float4*)WkL)[tid] = u;
    }
    if (tid < 32) { bqL[tid] = bq[tid]; bkL[tid] = bk[tid]; }
    if (tid < 31) { WpL[tid] = Wp[tid]; bpL[tid] = bp[tid]; }
    if (tid == 0) { wl0 = Wl[0]; bl0 = bl[0]; }
    __syncthreads();

    const int p = blockIdx.x * 256 + tid;      // 0..4095
    const float t = ts[p];
    float e[32];
    e[0] = t * wl0 + bl0;
    #pragma unroll
    for (int j = 1; j < 32; ++j) e[j] = sinf(t * WpL[j - 1] + bpL[j - 1]);

    const int b = p >> 9, l = p & 511;
    float4* qm4 = (float4*)(qmat + (size_t)p * 32);
    float*  kT  = kmatT + (size_t)b * 32 * 512 + l;

    for (int dq = 0; dq < 8; ++dq) {
        float q0 = bqL[4*dq+0], q1 = bqL[4*dq+1], q2 = bqL[4*dq+2], q3 = bqL[4*dq+3];
        float k0 = bkL[4*dq+0], k1 = bkL[4*dq+1], k2 = bkL[4*dq+2], k3 = bkL[4*dq+3];
        const float* wq = &WqL[(4*dq) * 32];
        const float* wk = &WkL[(4*dq) * 32];
        #pragma unroll
        for (int j = 0; j < 32; ++j) {
            const float ej = e[j];
            q0 = fmaf(wq[j],      ej, q0);
            q1 = fmaf(wq[32 + j], ej, q1);
            q2 = fmaf(wq[64 + j], ej, q2);
            q3 = fmaf(wq[96 + j], ej, q3);
            k0 = fmaf(wk[j],      ej, k0);
            k1 = fmaf(wk[32 + j], ej, k1);
            k2 = fmaf(wk[64 + j], ej, k2);
            k3 = fmaf(wk[96 + j], ej, k3);
        }
        qm4[dq] = make_float4(q0, q1, q2, q3);
        kT[(4*dq + 0) * 512] = k0;
        kT[(4*dq + 1) * 512] = k1;
        kT[(4*dq + 2) * 512] = k2;
        kT[(4*dq + 3) * 512] = k3;
    }
}

// ---------------------------------------------------------------------------
// Kernel 2: per-(b,q) attention -> att_out.  grid (32 qb, 8 b), 256 thr.
// ---------------------------------------------------------------------------
__global__ __launch_bounds__(256) void k_attn(
    const float* __restrict__ qmat, const float* __restrict__ kmatT,
    const float* __restrict__ val,  const int*   __restrict__ mark,
    const float* __restrict__ npm,  const float* __restrict__ Wo,
    const float* __restrict__ bo,   float* __restrict__ att)
{
    __shared__ float srow[4 * 512];   // per-wave score row
    __shared__ int   cc[512];         // category (-1 if padded)
    __shared__ float vv[512];         // values
    const int tid = threadIdx.x;
    const int qb  = blockIdx.x;       // 0..31
    const int b   = blockIdx.y;       // 0..7

    for (int k = tid; k < 512; k += 256) {
        const int   m  = mark[b * 512 + k];
        const float np = npm[b * 512 + k];
        cc[k] = (np > 0.0f) ? (m - 1) : -1;
        vv[k] = val[b * 512 + k];
    }
    __syncthreads();

    const int w = tid >> 6, lane = tid & 63;
    const float* kTb = kmatT + (size_t)b * 32 * 512;

    for (int iq = 0; iq < 4; ++iq) {
        const int q = qb * 16 + w * 4 + iq;

        float qr[32];
        const float4* qm4 = (const float4*)(qmat + (size_t)(b * 512 + q) * 32);
        #pragma unroll
        for (int j4 = 0; j4 < 8; ++j4) {
            float4 v = qm4[j4];
            qr[4*j4+0] = v.x; qr[4*j4+1] = v.y; qr[4*j4+2] = v.z; qr[4*j4+3] = v.w;
        }

        float acc[8];
        #pragma unroll
        for (int m = 0; m < 8; ++m) acc[m] = 0.0f;
        #pragma unroll 4
        for (int j = 0; j < 32; ++j) {
            const float* row = kTb + j * 512 + lane;
            const float  qj  = qr[j];
            #pragma unroll
            for (int m = 0; m < 8; ++m) acc[m] = fmaf(qj, row[m * 64], acc[m]);
        }
        #pragma unroll
        for (int m = 0; m < 8; ++m)
            srow[w * 512 + m * 64 + lane] = acc[m] * 0.17677669529663687f;
        __syncthreads();

        const int c = lane & 15, s = lane >> 4;
        float mx = -1e30f, Z = 0.0f, X = 0.0f;
        const int base = s * 128;
        for (int t = 0; t < 128; ++t) {
            const int k = base + ((t + s) & 127);
            if (cc[k] == c) {
                const float l  = (k <= q + WOFF_) ? srow[w * 512 + k] : 0.0f;
                const float mn = fmaxf(mx, l);
                const float e1 = __expf(l - mn);
                const float sc = __expf(mx - mn);
                Z = Z * sc + e1;
                X = X * sc + e1 * vv[k];
                mx = mn;
            }
        }
        #pragma unroll
        for (int off = 16; off <= 32; off <<= 1) {
            const float mo = __shfl_xor(mx, off);
            const float Zo = __shfl_xor(Z, off);
            const float Xo = __shfl_xor(X, off);
            const float mn = fmaxf(mx, mo);
            const float a0 = __expf(mx - mn);
            const float a1 = __expf(mo - mn);
            Z = Z * a0 + Zo * a1;
            X = X * a0 + Xo * a1;
            mx = mn;
        }
        const float x = (Z > 0.0f) ? X / Z : 0.0f;

        float xs[16];
        #pragma unroll
        for (int c2 = 0; c2 < 16; ++c2) xs[c2] = __shfl(x, c2);

        const float4* wo4 = (const float4*)(Wo + lane * 16);
        float a = bo[lane];
        #pragma unroll
        for (int c4 = 0; c4 < 4; ++c4) {
            float4 v = wo4[c4];
            a += xs[4*c4+0] * v.x + xs[4*c4+1] * v.y + xs[4*c4+2] * v.z + xs[4*c4+3] * v.w;
        }
        att[(size_t)(b * 512 + q) * 64 + lane] = a;
        __syncthreads();
    }
}

// ---------------------------------------------------------------------------
// Kernel 3: gi = att @ W_ih^T + b_ih.  256 blocks x 16 rows each.
// ---------------------------------------------------------------------------
__global__ __launch_bounds__(256) void k_gi(
    const float* __restrict__ att, const float* __restrict__ Wih,
    const float* __restrict__ bih, float* __restrict__ gi)
{
    __shared__ float WL[192 * 65];
    __shared__ float attL[16 * 64];
    __shared__ float bL[192];
    const int tid = threadIdx.x;

    for (int idx = tid; idx < 3072; idx += 256) {
        float4 v = ((const float4*)Wih)[idx];
        const int g = idx >> 4, jq = idx & 15;
        float* dst = &WL[g * 65 + jq * 4];
        dst[0] = v.x; dst[1] = v.y; dst[2] = v.z; dst[3] = v.w;
    }
    if (tid < 192) bL[tid] = bih[tid];
    {
        float4 v = ((const float4*)att)[blockIdx.x * 256 + tid];
        ((float4*)attL)[tid] = v;
    }
    __syncthreads();

    const size_t out0 = (size_t)blockIdx.x * 16 * 192;
    for (int pp = 0; pp < 12; ++pp) {
        const int p = tid + 256 * pp;
        const int r = p / 192, g = p - r * 192;
        float a0 = bL[g], a1 = 0.f, a2 = 0.f, a3 = 0.f;
        const float* wrow = &WL[g * 65];
        const float* arow = &attL[r * 64];
        #pragma unroll
        for (int j = 0; j < 64; j += 4) {
            a0 = fmaf(arow[j + 0], wrow[j + 0], a0);
            a1 = fmaf(arow[j + 1], wrow[j + 1], a1);
            a2 = fmaf(arow[j + 2], wrow[j + 2], a2);
            a3 = fmaf(arow[j + 3], wrow[j + 3], a3);
        }
        gi[out0 + p] = (a0 + a1) + (a2 + a3);
    }
}

// ---------------------------------------------------------------------------
// Kernel 4: sequential GRU — one WAVE per batch, no barriers, no LDS.
// Lane i owns h_i and W_hh rows (i, i+64, i+128) in registers.
// h broadcast each step via v_readlane (wave-synchronous).
// gi[t+1] register-prefetched during step t's matvec.
// ---------------------------------------------------------------------------
__device__ __forceinline__ float bcast_lane(float v, int j) {
    return __uint_as_float(__builtin_amdgcn_readlane(__float_as_uint(v), j));
}

__global__ __launch_bounds__(64) void k_gru(
    const float* __restrict__ gi, const float* __restrict__ Whh,
    const float* __restrict__ bhh, float* __restrict__ out)
{
    const int lane = threadIdx.x;     // 0..63
    const int b    = blockIdx.x;      // 0..7

    // Stage this lane's three W_hh rows into registers.
    float wr[64], wz[64], wn[64];
    {
        const float4* r4 = (const float4*)(Whh + (size_t)lane * 64);
        const float4* z4 = (const float4*)(Whh + (size_t)(lane + 64) * 64);
        const float4* n4 = (const float4*)(Whh + (size_t)(lane + 128) * 64);
        #pragma unroll
        for (int j4 = 0; j4 < 16; ++j4) {
            float4 a = r4[j4];
            wr[4*j4+0] = a.x; wr[4*j4+1] = a.y; wr[4*j4+2] = a.z; wr[4*j4+3] = a.w;
            float4 c = z4[j4];
            wz[4*j4+0] = c.x; wz[4*j4+1] = c.y; wz[4*j4+2] = c.z; wz[4*j4+3] = c.w;
            float4 d = n4[j4];
            wn[4*j4+0] = d.x; wn[4*j4+1] = d.y; wn[4*j4+2] = d.z; wn[4*j4+3] = d.w;
        }
    }
    const float br = bhh[lane];
    const float bz = bhh[lane + 64];
    const float bn = bhh[lane + 128];

    const float* gib  = gi  + (size_t)b * 512 * 192;
    float*       outb = out + (size_t)b * 512 * 64;

    float h = 0.0f;

    // prefetch gi[0]
    float gr = gib[lane], gz = gib[lane + 64], gn = gib[lane + 128];

    for (int t = 0; t < 512; ++t) {
        // issue next step's gi loads now; consumed next iteration
        const int tn = (t + 1 < 512) ? (t + 1) : 511;
        const float* gin = gib + (size_t)tn * 192;
        const float gr_n = gin[lane];
        const float gz_n = gin[lane + 64];
        const float gn_n = gin[lane + 128];

        // matvec: hr/hz/hn for this lane's rows.  ar/az fold in gi + bias.
        float ar = gr + br;
        float az = gz + bz;
        float hn = bn;
        #pragma unroll
        for (int j = 0; j < 64; ++j) {
            const float hj = bcast_lane(h, j);
            ar = fmaf(wr[j], hj, ar);
            az = fmaf(wz[j], hj, az);
            hn = fmaf(wn[j], hj, hn);
        }

        // activations (fast rcp; |err| ~1 ulp, far below threshold)
        const float r = __builtin_amdgcn_rcpf(1.0f + __expf(-ar));
        const float z = __builtin_amdgcn_rcpf(1.0f + __expf(-az));
        float npre = gn + r * hn;
        npre = fminf(fmaxf(npre, -15.0f), 15.0f);
        const float e2 = __expf(2.0f * npre);
        const float n  = (e2 - 1.0f) * __builtin_amdgcn_rcpf(e2 + 1.0f);

        h = fmaf(z, h - n, n);            // (1-z)*n + z*h
        outb[t * 64 + lane] = h;

        gr = gr_n; gz = gz_n; gn = gn_n;
    }
}

// ---------------------------------------------------------------------------
extern "C" void kernel_launch(void* const* d_in, const int* in_sizes, int n_in,
                              void* d_out, int out_size, void* d_ws, size_t ws_size,
                              hipStream_t stream)
{
    const float* ts   = (const float*)d_in[0];
    const float* val  = (const float*)d_in[1];
    const int*   mark = (const int*)  d_in[2];
    const float* npm  = (const float*)d_in[3];
    const float* Wl   = (const float*)d_in[4];
    const float* bl   = (const float*)d_in[5];
    const float* Wp   = (const float*)d_in[6];
    const float* bp   = (const float*)d_in[7];
    const float* Wq   = (const float*)d_in[8];
    const float* bq   = (const float*)d_in[9];
    const float* Wk   = (const float*)d_in[10];
    const float* bk   = (const float*)d_in[11];
    const float* Wo   = (const float*)d_in[12];
    const float* bo   = (const float*)d_in[13];
    const float* Wih  = (const float*)d_in[14];
    const float* Whh  = (const float*)d_in[15];
    const float* bih  = (const float*)d_in[16];
    const float* bhh  = (const float*)d_in[17];

    float* ws    = (float*)d_ws;
    float* qmat  = ws;                 // 131072
    float* kmatT = ws + 131072;        // 131072
    float* att   = ws + 262144;        // 262144
    float* gi    = ws + 524288;        // 786432
    float* out   = (float*)d_out;

    k_embed<<<16, 256, 0, stream>>>(ts, Wl, bl, Wp, bp, Wq, bq, Wk, bk, qmat, kmatT);
    k_attn<<<dim3(32, 8), 256, 0, stream>>>(qmat, kmatT, val, mark, npm, Wo, bo, att);
    k_gi<<<256, 256, 0, stream>>>(att, Wih, bih, gi);
    k_gru<<<8, 192 / 3, 0, stream>>>(gi, Whh, bhh, out);
}

// Round 3
// 474.626 us; speedup vs baseline: 1.4036x; 1.3833x over previous
//
#include <hip/hip_runtime.h>
#include <math.h>

// Problem constants
#define B_    8
#define L_    512
#define K_    16
#define E_    32
#define NH_   64
#define WOFF_ 1

// Workspace layout (floats):
//   qmat  [B][L][32]   @ 0        (131072)
//   kmatT [B][32][L]   @ 131072   (131072)
//   att   [B][L][64]   @ 262144   (262144)
//   gi    [B][L][192]  @ 524288   (786432)

typedef float v2f __attribute__((ext_vector_type(2)));

// ---------------------------------------------------------------------------
// Kernel 1: key_emb -> q, k projections. One thread per (b,l).
// ---------------------------------------------------------------------------
__global__ __launch_bounds__(256) void k_embed(
    const float* __restrict__ ts, const float* __restrict__ Wl,
    const float* __restrict__ bl, const float* __restrict__ Wp,
    const float* __restrict__ bp, const float* __restrict__ Wq,
    const float* __restrict__ bq, const float* __restrict__ Wk,
    const float* __restrict__ bk,
    float* __restrict__ qmat, float* __restrict__ kmatT)
{
    __shared__ float WqL[1024], WkL[1024];
    __shared__ float bqL[32], bkL[32], WpL[31], bpL[31];
    __shared__ float wl0, bl0;
    const int tid = threadIdx.x;

    {
        float4 v = ((const float4*)Wq)[tid];
        ((float4*)WqL)[tid] = v;
        float4 u = ((const float4*)Wk)[tid];
        ((float4*)WkL)[tid] = u;
    }
    if (tid < 32) { bqL[tid] = bq[tid]; bkL[tid] = bk[tid]; }
    if (tid < 31) { WpL[tid] = Wp[tid]; bpL[tid] = bp[tid]; }
    if (tid == 0) { wl0 = Wl[0]; bl0 = bl[0]; }
    __syncthreads();

    const int p = blockIdx.x * 256 + tid;      // 0..4095
    const float t = ts[p];
    float e[32];
    e[0] = t * wl0 + bl0;
    #pragma unroll
    for (int j = 1; j < 32; ++j) e[j] = sinf(t * WpL[j - 1] + bpL[j - 1]);

    const int b = p >> 9, l = p & 511;
    float4* qm4 = (float4*)(qmat + (size_t)p * 32);
    float*  kT  = kmatT + (size_t)b * 32 * 512 + l;

    for (int dq = 0; dq < 8; ++dq) {
        float q0 = bqL[4*dq+0], q1 = bqL[4*dq+1], q2 = bqL[4*dq+2], q3 = bqL[4*dq+3];
        float k0 = bkL[4*dq+0], k1 = bkL[4*dq+1], k2 = bkL[4*dq+2], k3 = bkL[4*dq+3];
        const float* wq = &WqL[(4*dq) * 32];
        const float* wk = &WkL[(4*dq) * 32];
        #pragma unroll
        for (int j = 0; j < 32; ++j) {
            const float ej = e[j];
            q0 = fmaf(wq[j],      ej, q0);
            q1 = fmaf(wq[32 + j], ej, q1);
            q2 = fmaf(wq[64 + j], ej, q2);
            q3 = fmaf(wq[96 + j], ej, q3);
            k0 = fmaf(wk[j],      ej, k0);
            k1 = fmaf(wk[32 + j], ej, k1);
            k2 = fmaf(wk[64 + j], ej, k2);
            k3 = fmaf(wk[96 + j], ej, k3);
        }
        qm4[dq] = make_float4(q0, q1, q2, q3);
        kT[(4*dq + 0) * 512] = k0;
        kT[(4*dq + 1) * 512] = k1;
        kT[(4*dq + 2) * 512] = k2;
        kT[(4*dq + 3) * 512] = k3;
    }
}

// ---------------------------------------------------------------------------
// Kernel 2: per-(b,q) attention -> att_out.  grid (32 qb, 8 b), 256 thr.
// ---------------------------------------------------------------------------
__global__ __launch_bounds__(256) void k_attn(
    const float* __restrict__ qmat, const float* __restrict__ kmatT,
    const float* __restrict__ val,  const int*   __restrict__ mark,
    const float* __restrict__ npm,  const float* __restrict__ Wo,
    const float* __restrict__ bo,   float* __restrict__ att)
{
    __shared__ float srow[4 * 512];   // per-wave score row
    __shared__ int   cc[512];         // category (-1 if padded)
    __shared__ float vv[512];         // values
    const int tid = threadIdx.x;
    const int qb  = blockIdx.x;       // 0..31
    const int b   = blockIdx.y;       // 0..7

    for (int k = tid; k < 512; k += 256) {
        const int   m  = mark[b * 512 + k];
        const float np = npm[b * 512 + k];
        cc[k] = (np > 0.0f) ? (m - 1) : -1;
        vv[k] = val[b * 512 + k];
    }
    __syncthreads();

    const int w = tid >> 6, lane = tid & 63;
    const float* kTb = kmatT + (size_t)b * 32 * 512;

    for (int iq = 0; iq < 4; ++iq) {
        const int q = qb * 16 + w * 4 + iq;

        float qr[32];
        const float4* qm4 = (const float4*)(qmat + (size_t)(b * 512 + q) * 32);
        #pragma unroll
        for (int j4 = 0; j4 < 8; ++j4) {
            float4 v = qm4[j4];
            qr[4*j4+0] = v.x; qr[4*j4+1] = v.y; qr[4*j4+2] = v.z; qr[4*j4+3] = v.w;
        }

        float acc[8];
        #pragma unroll
        for (int m = 0; m < 8; ++m) acc[m] = 0.0f;
        #pragma unroll 4
        for (int j = 0; j < 32; ++j) {
            const float* row = kTb + j * 512 + lane;
            const float  qj  = qr[j];
            #pragma unroll
            for (int m = 0; m < 8; ++m) acc[m] = fmaf(qj, row[m * 64], acc[m]);
        }
        #pragma unroll
        for (int m = 0; m < 8; ++m)
            srow[w * 512 + m * 64 + lane] = acc[m] * 0.17677669529663687f;
        __syncthreads();

        const int c = lane & 15, s = lane >> 4;
        float mx = -1e30f, Z = 0.0f, X = 0.0f;
        const int base = s * 128;
        for (int t = 0; t < 128; ++t) {
            const int k = base + ((t + s) & 127);
            if (cc[k] == c) {
                const float l  = (k <= q + WOFF_) ? srow[w * 512 + k] : 0.0f;
                const float mn = fmaxf(mx, l);
                const float e1 = __expf(l - mn);
                const float sc = __expf(mx - mn);
                Z = Z * sc + e1;
                X = X * sc + e1 * vv[k];
                mx = mn;
            }
        }
        #pragma unroll
        for (int off = 16; off <= 32; off <<= 1) {
            const float mo = __shfl_xor(mx, off);
            const float Zo = __shfl_xor(Z, off);
            const float Xo = __shfl_xor(X, off);
            const float mn = fmaxf(mx, mo);
            const float a0 = __expf(mx - mn);
            const float a1 = __expf(mo - mn);
            Z = Z * a0 + Zo * a1;
            X = X * a0 + Xo * a1;
            mx = mn;
        }
        const float x = (Z > 0.0f) ? X / Z : 0.0f;

        float xs[16];
        #pragma unroll
        for (int c2 = 0; c2 < 16; ++c2) xs[c2] = __shfl(x, c2);

        const float4* wo4 = (const float4*)(Wo + lane * 16);
        float a = bo[lane];
        #pragma unroll
        for (int c4 = 0; c4 < 4; ++c4) {
            float4 v = wo4[c4];
            a += xs[4*c4+0] * v.x + xs[4*c4+1] * v.y + xs[4*c4+2] * v.z + xs[4*c4+3] * v.w;
        }
        att[(size_t)(b * 512 + q) * 64 + lane] = a;
        __syncthreads();
    }
}

// ---------------------------------------------------------------------------
// Kernel 3: gi = att @ W_ih^T + b_ih.  256 blocks x 16 rows each.
// ---------------------------------------------------------------------------
__global__ __launch_bounds__(256) void k_gi(
    const float* __restrict__ att, const float* __restrict__ Wih,
    const float* __restrict__ bih, float* __restrict__ gi)
{
    __shared__ float WL[192 * 65];
    __shared__ float attL[16 * 64];
    __shared__ float bL[192];
    const int tid = threadIdx.x;

    for (int idx = tid; idx < 3072; idx += 256) {
        float4 v = ((const float4*)Wih)[idx];
        const int g = idx >> 4, jq = idx & 15;
        float* dst = &WL[g * 65 + jq * 4];
        dst[0] = v.x; dst[1] = v.y; dst[2] = v.z; dst[3] = v.w;
    }
    if (tid < 192) bL[tid] = bih[tid];
    {
        float4 v = ((const float4*)att)[blockIdx.x * 256 + tid];
        ((float4*)attL)[tid] = v;
    }
    __syncthreads();

    const size_t out0 = (size_t)blockIdx.x * 16 * 192;
    for (int pp = 0; pp < 12; ++pp) {
        const int p = tid + 256 * pp;
        const int r = p / 192, g = p - r * 192;
        float a0 = bL[g], a1 = 0.f, a2 = 0.f, a3 = 0.f;
        const float* wrow = &WL[g * 65];
        const float* arow = &attL[r * 64];
        #pragma unroll
        for (int j = 0; j < 64; j += 4) {
            a0 = fmaf(arow[j + 0], wrow[j + 0], a0);
            a1 = fmaf(arow[j + 1], wrow[j + 1], a1);
            a2 = fmaf(arow[j + 2], wrow[j + 2], a2);
            a3 = fmaf(arow[j + 3], wrow[j + 3], a3);
        }
        gi[out0 + p] = (a0 + a1) + (a2 + a3);
    }
}

// ---------------------------------------------------------------------------
// Kernel 4: sequential GRU — one WAVE per batch, no barriers, no LDS.
// Lane i owns h_i and W_hh rows (i, i+64, i+128) in registers.
// __launch_bounds__(64, 1): min 1 wave/EU -> VGPR cap 512, so the 192
// weight floats stay register-resident (round-2 failure: default occupancy
// target capped VGPRs at 104 and spilled all weights to scratch).
// Matvec packed as v2f (2-wide ext vector) to get v_pk_fma_f32 dual-issue.
// ---------------------------------------------------------------------------
__device__ __forceinline__ float bcast_lane(float v, int j) {
    return __uint_as_float(__builtin_amdgcn_readlane(__float_as_uint(v), j));
}

__global__ __launch_bounds__(64, 1) void k_gru(
    const float* __restrict__ gi, const float* __restrict__ Whh,
    const float* __restrict__ bhh, float* __restrict__ out)
{
    const int lane = threadIdx.x;     // 0..63
    const int b    = blockIdx.x;      // 0..7

    // Stage this lane's three W_hh rows into registers (as 32 x v2f each).
    v2f wr[32], wz[32], wn[32];
    {
        const v2f* r2 = (const v2f*)(Whh + (size_t)lane * 64);
        const v2f* z2 = (const v2f*)(Whh + (size_t)(lane + 64) * 64);
        const v2f* n2 = (const v2f*)(Whh + (size_t)(lane + 128) * 64);
        #pragma unroll
        for (int j = 0; j < 32; ++j) {
            wr[j] = r2[j];
            wz[j] = z2[j];
            wn[j] = n2[j];
        }
    }
    const float br = bhh[lane];
    const float bz = bhh[lane + 64];
    const float bn = bhh[lane + 128];

    const float* gib  = gi  + (size_t)b * 512 * 192;
    float*       outb = out + (size_t)b * 512 * 64;

    float h = 0.0f;

    // prefetch gi[0]
    float gr = gib[lane], gz = gib[lane + 64], gn = gib[lane + 128];

    for (int t = 0; t < 512; ++t) {
        // issue next step's gi loads now; consumed next iteration
        const int tn = (t + 1 < 512) ? (t + 1) : 511;
        const float* gin = gib + (size_t)tn * 192;
        const float gr_n = gin[lane];
        const float gz_n = gin[lane + 64];
        const float gn_n = gin[lane + 128];

        // matvec via packed fp32: ar2/az2/an2 accumulate pairs.
        v2f ar2 = {gr + br, 0.0f};
        v2f az2 = {gz + bz, 0.0f};
        v2f an2 = {bn, 0.0f};
        #pragma unroll
        for (int j = 0; j < 32; ++j) {
            v2f hp;
            hp.x = bcast_lane(h, 2 * j);
            hp.y = bcast_lane(h, 2 * j + 1);
            ar2 = wr[j] * hp + ar2;       // -> v_pk_fma_f32
            az2 = wz[j] * hp + az2;
            an2 = wn[j] * hp + an2;
        }
        const float ar = ar2.x + ar2.y;
        const float az = az2.x + az2.y;
        const float hn = an2.x + an2.y;

        // activations (fast rcp; |err| ~1 ulp, far below threshold)
        const float r = __builtin_amdgcn_rcpf(1.0f + __expf(-ar));
        const float z = __builtin_amdgcn_rcpf(1.0f + __expf(-az));
        float npre = gn + r * hn;
        npre = fminf(fmaxf(npre, -15.0f), 15.0f);
        const float e2 = __expf(2.0f * npre);
        const float n  = (e2 - 1.0f) * __builtin_amdgcn_rcpf(e2 + 1.0f);

        h = fmaf(z, h - n, n);            // (1-z)*n + z*h
        outb[t * 64 + lane] = h;

        gr = gr_n; gz = gz_n; gn = gn_n;
    }
}

// ---------------------------------------------------------------------------
extern "C" void kernel_launch(void* const* d_in, const int* in_sizes, int n_in,
                              void* d_out, int out_size, void* d_ws, size_t ws_size,
                              hipStream_t stream)
{
    const float* ts   = (const float*)d_in[0];
    const float* val  = (const float*)d_in[1];
    const int*   mark = (const int*)  d_in[2];
    const float* npm  = (const float*)d_in[3];
    const float* Wl   = (const float*)d_in[4];
    const float* bl   = (const float*)d_in[5];
    const float* Wp   = (const float*)d_in[6];
    const float* bp   = (const float*)d_in[7];
    const float* Wq   = (const float*)d_in[8];
    const float* bq   = (const float*)d_in[9];
    const float* Wk   = (const float*)d_in[10];
    const float* bk   = (const float*)d_in[11];
    const float* Wo   = (const float*)d_in[12];
    const float* bo   = (const float*)d_in[13];
    const float* Wih  = (const float*)d_in[14];
    const float* Whh  = (const float*)d_in[15];
    const float* bih  = (const float*)d_in[16];
    const float* bhh  = (const float*)d_in[17];

    float* ws    = (float*)d_ws;
    float* qmat  = ws;                 // 131072
    float* kmatT = ws + 131072;        // 131072
    float* att   = ws + 262144;        // 262144
    float* gi    = ws + 524288;        // 786432
    float* out   = (float*)d_out;

    k_embed<<<16, 256, 0, stream>>>(ts, Wl, bl, Wp, bp, Wq, bq, Wk, bk, qmat, kmatT);
    k_attn<<<dim3(32, 8), 256, 0, stream>>>(qmat, kmatT, val, mark, npm, Wo, bo, att);
    k_gi<<<256, 256, 0, stream>>>(att, Wih, bih, gi);
    k_gru<<<8, 64, 0, stream>>>(gi, Whh, bhh, out);
}